// Round 2
// baseline (2994.954 us; speedup 1.0000x reference)
//
#include <hip/hip_runtime.h>
#include <stdint.h>

// Forbid mul+add contraction: distance arithmetic must match the numpy
// reference bit-for-bit (argmax / radius-compare are discontinuous).
// MLP math uses explicit fmaf() (exact FMA is fine; only ordering matters).
#pragma clang fp contract(off)

#define NPT   16384
#define BB    8
#define SS    1024
#define KSAMP 32
#define PTOT  (BB*SS*KSAMP)   // 262144
#define NGRP  (BB*SS)         // 8192
#define R2    0.04f
#define EPSBN 1e-5f
#define INV_M 3.814697265625e-06f   // 1/262144, exact power of two

// ws layout (floats)
#define OFF_S1 0
#define OFF_Q1 64
#define OFF_S2 128
#define OFF_Q2 192
#define OFF_S3 256    // 128
#define OFF_Q3 384    // 128
#define OFF_A1 512
#define OFF_C1 576
#define OFF_A2 640
#define OFF_C2 704
#define OFF_A3 768    // 128
#define OFF_C3 896    // 128
#define OFF_ZMAX 1024                  // 8192*128 = 1048576
#define OFF_FEAT (1024 + 1048576)      // 6*262144 = 1572864  (total ~10.5 MB)

// ---------------------------------------------------------------------------
// helpers
// ---------------------------------------------------------------------------
__device__ __forceinline__ float wave_sum(float v) {
#pragma unroll
  for (int off = 32; off; off >>= 1) v += __shfl_xor(v, off);
  return v;  // butterfly: all lanes hold identical total
}
__device__ __forceinline__ float half_max(float v) {
#pragma unroll
  for (int off = 16; off; off >>= 1) v = fmaxf(v, __shfl_xor(v, off));
  return v;  // max within each 32-lane half
}

// ---------------------------------------------------------------------------
// 1) Farthest point sampling. R2 POST-MORTEM: 2.09us/iter = 5000cy; VALUBusy
//    68% on active CUs -> ~3400cy VALU issue/SIMD/iter (2.2x the distance-
//    arith floor). Extra ops: in-loop argmax (cmp+2 cndmask+index mat per
//    point), LDS addr recompute for offsets >64KiB imm, redundant 8xu64
//    scalar reduce in every thread. Plus serial L2 centroid load (~250cy)
//    every iteration and only 2 waves/SIMD to hide DS latency.
//    R3 STRUCTURE:
//    - 1024 thr x 16 pts: 4 waves/SIMD; z[16],d[16] regs (~32 + temps VGPR).
//    - value-only inner loop (fmin+fmax, 10 VALU/pt); index/z recovered
//      post-loop with inline-const cndmask scan (d[j]==bv, descending j
//      -> lowest j, matching jnp.argmax first-occurrence).
//    - two base pointers so all 16 ds_read_b64 use imm offsets (<64KiB).
//    - two-phase wave argmax: f32 v_max butterfly then u32 v_min on
//      candidate index (12 shfl, 12 VALU).
//    - cooperative cross-wave reduce: lane reads entry (lane&15), 4-step
//      (key,z)-carry butterfly; winner's z carried, cx/cy from LDS ->
//      ZERO global loads in the loop (serial L2 fetch eliminated).
//    Distance arithmetic order unchanged (bit-exact): (dx*dx+dy*dy)+dz*dz,
//    fminf, with centroid coords bitwise-identical copies from LDS/regs.
// ---------------------------------------------------------------------------
__global__ __launch_bounds__(1024)
void fps_kernel(const float* __restrict__ xyz, float* __restrict__ newxyz) {
  extern __shared__ float smem[];          // 128 KiB dynamic: float2 sxy[NPT]
  float2* sxy = (float2*)smem;
  const int b = blockIdx.x;
  const int t = threadIdx.x;
  const int lane = t & 63;
  const int w = t >> 6;                    // 16 waves
  const float* xb = xyz + (size_t)b * NPT * 3;

  float z[16], d[16];
#pragma unroll
  for (int j = 0; j < 16; ++j) {
    int p = j * 1024 + t;
    float xx = xb[3 * p];
    float yy = xb[3 * p + 1];
    float zz = xb[3 * p + 2];
    sxy[p] = make_float2(xx, yy);
    z[j] = zz;
    d[j] = 1e10f;
    asm volatile("" : "+v"(z[j]));        // keep z materialized in a VGPR
  }

  __shared__ unsigned long long rk[2][16]; // per-wave (vmax, ~minidx) keys
  __shared__ float rz[2][16];              // per-wave winner z

  // initial centroid = point 0 (uniform broadcast loads, once)
  float cx = xb[0], cy = xb[1], cz = xb[2];
  if (t == 0) {
    float* o = newxyz + (size_t)b * SS * 3;
    o[0] = cx; o[1] = cy; o[2] = cz;
  }
  __syncthreads();                         // sxy visible to all waves

  // two bases so every ds_read_b64 gets an immediate offset < 64KiB:
  // pA[j*1024] covers j=0..7 (byte offs 0..57344), pB likewise for j=8..15.
  const float2* pA = sxy + t;
  const float2* pB = sxy + t + 8192;

  for (int it = 1; it < SS; ++it) {
    float bv = -1.0f;
#pragma unroll
    for (int j = 0; j < 16; ++j) {
      float2 xy = (j < 8) ? pA[j * 1024] : pB[(j - 8) * 1024];
      float dx = xy.x - cx, dy = xy.y - cy, dz = z[j] - cz;
      float d2 = (dx * dx + dy * dy) + dz * dz;   // matches numpy order
      float dm = fminf(d[j], d2);
      d[j] = dm;
      bv = fmaxf(bv, dm);                 // value-only tracking
    }
    // post-loop recovery: lowest j with d[j]==bv (fmax returns an operand
    // bitwise, so equality holds for the max). Inline-const j in cndmask.
    int bj = 0; float zc = z[0];
#pragma unroll
    for (int j = 15; j >= 0; --j) {
      bool m = (d[j] == bv);
      bj = m ? j : bj;
      zc = m ? z[j] : zc;
    }
    int bi = bj * 1024 + t;               // global index within batch

    // phase 1: wave max of value (v_max_f32 butterfly)
    float vmax = bv;
#pragma unroll
    for (int off = 32; off; off >>= 1) vmax = fmaxf(vmax, __shfl_xor(vmax, off));
    // phase 2: wave min index among vmax holders (v_min-style butterfly)
    unsigned cand = (bv == vmax) ? (unsigned)bi : 0xffffffffu;
#pragma unroll
    for (int off = 32; off; off >>= 1) {
      unsigned o = (unsigned)__shfl_xor((int)cand, off);
      cand = (o < cand) ? o : cand;
    }
    const int buf = it & 1;
    if (lane == 0)
      rk[buf][w] = ((unsigned long long)__float_as_uint(vmax) << 32) |
                   (unsigned)(~cand);
    if ((unsigned)bi == cand) rz[buf][w] = zc;   // unique owner publishes z
    __syncthreads();
    // single barrier per iter is safe: next iteration writes the OTHER
    // buffer; the barrier of it+1 orders those writes after these reads.

    // cross-wave: each lane holds entry (lane&15); 4-step carry butterfly
    // (xor 1,2,4,8 stays within each 16-lane group; all groups identical).
    unsigned long long k = rk[buf][lane & 15];
    float zk = rz[buf][lane & 15];
#pragma unroll
    for (int off = 8; off; off >>= 1) {
      unsigned long long ok = __shfl_xor(k, off);
      float oz = __shfl_xor(zk, off);
      if (ok > k) { k = ok; zk = oz; }
    }
    int fi = (int)(~(unsigned)k);
    fi = __builtin_amdgcn_readfirstlane(fi);     // uniform
    float2 cxy = sxy[fi];                        // LDS broadcast read
    cx = cxy.x; cy = cxy.y; cz = zk;
    if (t == 0) {
      float* o = newxyz + ((size_t)b * SS + it) * 3;
      o[0] = cx; o[1] = cy; o[2] = cz;
    }
  }
}

// ---------------------------------------------------------------------------
// 2) Ball query + gather (fused): one wave per centroid, ascending-index scan
//    with ballot == ref's sort+slice. feat is channel-major [6][PTOT].
// ---------------------------------------------------------------------------
__global__ __launch_bounds__(256, 2)
void ballq_kernel(const float* __restrict__ xyz, const float* __restrict__ pts,
                  const float* __restrict__ newxyz, float* __restrict__ feat) {
  const int lane = threadIdx.x & 63;
  const int c = blockIdx.x * 4 + (threadIdx.x >> 6);  // 0..8191
  const int b = c >> 10;
  const float* xb = xyz + (size_t)b * NPT * 3;
  const float* pb = pts + (size_t)b * NPT * 3;
  const float cx = newxyz[3 * c], cy = newxyz[3 * c + 1], cz = newxyz[3 * c + 2];
  const int base = c * KSAMP;
  const uint64_t ltm = (1ull << lane) - 1ull;

  int cnt = 0, firstp = 0;
  bool haveFirst = false;
  for (int p0 = 0; p0 < NPT && cnt < KSAMP; p0 += 64) {
    int p = p0 + lane;
    float px = xb[3 * p], py = xb[3 * p + 1], pz = xb[3 * p + 2];
    float dx = cx - px, dy = cy - py, dz = cz - pz;
    float sqr = (dx * dx + dy * dy) + dz * dz;
    bool in = (sqr <= R2);                          // !(sqr > r^2)
    uint64_t m = __ballot(in);
    if (!haveFirst && m) { firstp = p0 + (__ffsll((unsigned long long)m) - 1); haveFirst = true; }
    int rank = (int)__popcll(m & ltm);
    int slot = cnt + rank;
    if (in && slot < KSAMP) {
      int idx = base + slot;
      feat[0 * PTOT + idx] = px - cx;
      feat[1 * PTOT + idx] = py - cy;
      feat[2 * PTOT + idx] = pz - cz;
      feat[3 * PTOT + idx] = pb[3 * p];
      feat[4 * PTOT + idx] = pb[3 * p + 1];
      feat[5 * PTOT + idx] = pb[3 * p + 2];
    }
    cnt += (int)__popcll(m);
  }
  if (cnt < KSAMP) {  // pad with first in-ball point (center itself qualifies)
    int slot = cnt + lane;
    if (slot < KSAMP) {
      int idx = base + slot;
      float px = xb[3 * firstp], py = xb[3 * firstp + 1], pz = xb[3 * firstp + 2];
      feat[0 * PTOT + idx] = px - cx;
      feat[1 * PTOT + idx] = py - cy;
      feat[2 * PTOT + idx] = pz - cz;
      feat[3 * PTOT + idx] = pb[3 * firstp];
      feat[4 * PTOT + idx] = pb[3 * firstp + 1];
      feat[5 * PTOT + idx] = pb[3 * firstp + 2];
    }
  }
}

// ---------------------------------------------------------------------------
// 3) stats of layer-1 pre-activations. Per-thread s[64],q[64] (cheap here:
//    only 6 FMA per channel). Block-reduce -> global atomics.
// ---------------------------------------------------------------------------
__global__ __launch_bounds__(256, 2)
void mlp1s_kernel(const float* __restrict__ feat, const float* __restrict__ w0,
                  const float* __restrict__ b0, float* __restrict__ stats) {
  float s[64], q[64];
#pragma unroll
  for (int o = 0; o < 64; ++o) { s[o] = 0.0f; q[o] = 0.0f; }
  int gid = blockIdx.x * 256 + threadIdx.x;
  for (int p = gid; p < PTOT; p += 256 * 256) {
    float f[6];
#pragma unroll
    for (int ch = 0; ch < 6; ++ch) f[ch] = feat[ch * PTOT + p];
#pragma unroll
    for (int o = 0; o < 64; ++o) {
      float z = b0[o];
#pragma unroll
      for (int i = 0; i < 6; ++i) z = fmaf(w0[o * 6 + i], f[i], z);
      s[o] += z; q[o] = fmaf(z, z, q[o]);
    }
  }
  const int lane = threadIdx.x & 63;
#pragma unroll
  for (int o = 0; o < 64; ++o) { s[o] = wave_sum(s[o]); q[o] = wave_sum(q[o]); }
  __shared__ float ls[128];
  if (threadIdx.x < 128) ls[threadIdx.x] = 0.0f;
  __syncthreads();
  if (lane == 0) {
#pragma unroll
    for (int o = 0; o < 64; ++o) { atomicAdd(&ls[o], s[o]); atomicAdd(&ls[64 + o], q[o]); }
  }
  __syncthreads();
  if (threadIdx.x < 64) atomicAdd(&stats[OFF_S1 + threadIdx.x], ls[threadIdx.x]);
  else if (threadIdx.x < 128) atomicAdd(&stats[OFF_Q1 + threadIdx.x - 64], ls[threadIdx.x]);
}

// ---------------------------------------------------------------------------
// BN fold: a = g/sqrt(var+eps), c = be - a*mu   (h = relu(a*z + c))
// ---------------------------------------------------------------------------
__global__ void fin_kernel(const float* __restrict__ g, const float* __restrict__ be,
                           const float* __restrict__ s, const float* __restrict__ q,
                           float* __restrict__ A, float* __restrict__ C, int Cn) {
  int o = blockIdx.x * blockDim.x + threadIdx.x;
  if (o >= Cn) return;
  float mu = s[o] * INV_M;
  float var = q[o] * INV_M - mu * mu;
  float a = g[o] / sqrtf(var + EPSBN);
  A[o] = a;
  C[o] = be[o] - a * mu;
}

// ---------------------------------------------------------------------------
// 4) stats of layer-2 pre-activations. h1 built explicitly (unrolled o),
//    then rolled-o loop: scalar z2 accumulators + wave-butterfly stats into
//    designated-lane registers.
// ---------------------------------------------------------------------------
__global__ __launch_bounds__(256, 2)
void mlp2s_kernel(const float* __restrict__ feat,
                  const float* __restrict__ w0, const float* __restrict__ b0,
                  const float* __restrict__ w1, const float* __restrict__ b1,
                  const float* __restrict__ par, float* __restrict__ stats) {
  const float* a1 = par + OFF_A1;
  const float* c1 = par + OFF_C1;
  const int lane = threadIdx.x & 63;
  float sp = 0.0f, qp = 0.0f;          // this lane's channel (== lane)
  int gid = blockIdx.x * 256 + threadIdx.x;
  for (int p = gid; p < PTOT; p += 512 * 256) {
    float f[6];
#pragma unroll
    for (int ch = 0; ch < 6; ++ch) f[ch] = feat[ch * PTOT + p];
    float h1[64];
#pragma unroll
    for (int o = 0; o < 64; ++o) {
      float z = b0[o];
#pragma unroll
      for (int i = 0; i < 6; ++i) z = fmaf(w0[o * 6 + i], f[i], z);
      h1[o] = fmaxf(fmaf(a1[o], z, c1[o]), 0.0f);
    }
    for (int o = 0; o < 64; o += 2) {   // rolled: scalar temps only
      float z0 = b1[o], z1 = b1[o + 1];
#pragma unroll
      for (int i = 0; i < 64; ++i) {
        z0 = fmaf(w1[o * 64 + i], h1[i], z0);
        z1 = fmaf(w1[(o + 1) * 64 + i], h1[i], z1);
      }
      float s0 = wave_sum(z0), q0 = wave_sum(z0 * z0);
      float s1 = wave_sum(z1), q1 = wave_sum(z1 * z1);
      if (lane == o)     { sp += s0; qp += q0; }
      if (lane == o + 1) { sp += s1; qp += q1; }
    }
  }
  atomicAdd(&stats[OFF_S2 + lane], sp);
  atomicAdd(&stats[OFF_Q2 + lane], qp);
}

// ---------------------------------------------------------------------------
// 5) layer-3 fused: recompute h1 (per-i, no array), accumulate h2[64]
//    (i-rolled, o-unrolled), then rolled-o layer-3 with butterfly stats +
//    half-wave max. Writes zmax[g][o] (raw pre-BN max; valid because a3>0
//    makes relu(a*z+c) monotone).
// ---------------------------------------------------------------------------
__global__ __launch_bounds__(256, 2)
void mlp3f_kernel(const float* __restrict__ feat,
                  const float* __restrict__ w0, const float* __restrict__ b0,
                  const float* __restrict__ w1, const float* __restrict__ b1,
                  const float* __restrict__ w2, const float* __restrict__ b2,
                  const float* __restrict__ par, float* __restrict__ stats,
                  float* __restrict__ zmax) {
  const float* a1 = par + OFF_A1;
  const float* c1 = par + OFF_C1;
  const float* a2 = par + OFF_A2;
  const float* c2 = par + OFF_C2;
  const int lane = threadIdx.x & 63;
  float sp0 = 0.0f, qp0 = 0.0f;        // channel lane
  float sp1 = 0.0f, qp1 = 0.0f;        // channel 64+lane
  int gid = blockIdx.x * 256 + threadIdx.x;
  for (int p = gid; p < PTOT; p += 512 * 256) {
    float f[6];
#pragma unroll
    for (int ch = 0; ch < 6; ++ch) f[ch] = feat[ch * PTOT + p];
    float h2[64];
#pragma unroll
    for (int o = 0; o < 64; ++o) h2[o] = b1[o];
    for (int i = 0; i < 64; ++i) {      // rolled; h1[i] recomputed (8 instr)
      float z = b0[i];
#pragma unroll
      for (int ch = 0; ch < 6; ++ch) z = fmaf(w0[i * 6 + ch], f[ch], z);
      float h1i = fmaxf(fmaf(a1[i], z, c1[i]), 0.0f);
#pragma unroll
      for (int o = 0; o < 64; ++o) h2[o] = fmaf(w1[o * 64 + i], h1i, h2[o]);
    }
#pragma unroll
    for (int o = 0; o < 64; ++o) h2[o] = fmaxf(fmaf(a2[o], h2[o], c2[o]), 0.0f);

    const int g = p >> 5;               // this lane's group
    for (int o = 0; o < 128; o += 2) {  // rolled: scalar temps
      float z0 = b2[o], z1 = b2[o + 1];
#pragma unroll
      for (int i = 0; i < 64; ++i) {
        z0 = fmaf(w2[o * 64 + i], h2[i], z0);
        z1 = fmaf(w2[(o + 1) * 64 + i], h2[i], z1);
      }
      float s0 = wave_sum(z0), q0 = wave_sum(z0 * z0);
      float s1 = wave_sum(z1), q1 = wave_sum(z1 * z1);
      if (lane == (o & 63))       { if (o < 64) { sp0 += s0; qp0 += q0; } else { sp1 += s0; qp1 += q0; } }
      if (lane == ((o + 1) & 63)) { if (o < 64) { sp0 += s1; qp0 += q1; } else { sp1 += s1; qp1 += q1; } }
      float m0 = half_max(z0), m1 = half_max(z1);
      if ((lane & 31) == (o & 31))       zmax[g * 128 + o]     = m0;
      if ((lane & 31) == ((o + 1) & 31)) zmax[g * 128 + o + 1] = m1;
    }
  }
  atomicAdd(&stats[OFF_S3 + lane], sp0);
  atomicAdd(&stats[OFF_Q3 + lane], qp0);
  atomicAdd(&stats[OFF_S3 + 64 + lane], sp1);
  atomicAdd(&stats[OFF_Q3 + 64 + lane], qp1);
}

// ---------------------------------------------------------------------------
// 6) epilogue: out2[g][c] = relu(a3[c]*zmax[g][c] + c3[c])
// ---------------------------------------------------------------------------
__global__ __launch_bounds__(256, 4)
void final_out_kernel(const float* __restrict__ zmax, const float* __restrict__ par,
                      float* __restrict__ out2) {
  const float* a3 = par + OFF_A3;
  const float* c3 = par + OFF_C3;
  int idx = blockIdx.x * 256 + threadIdx.x;   // g*128 + c
  int c = idx & 127;
  out2[idx] = fmaxf(fmaf(a3[c], zmax[idx], c3[c]), 0.0f);
}

// ---------------------------------------------------------------------------
extern "C" void kernel_launch(void* const* d_in, const int* in_sizes, int n_in,
                              void* d_out, int out_size, void* d_ws, size_t ws_size,
                              hipStream_t stream) {
  const float* xyz = (const float*)d_in[0];
  const float* pts = (const float*)d_in[1];
  const float* w0  = (const float*)d_in[2];
  const float* b0  = (const float*)d_in[3];
  const float* g0  = (const float*)d_in[4];
  const float* be0 = (const float*)d_in[5];
  const float* w1  = (const float*)d_in[6];
  const float* b1  = (const float*)d_in[7];
  const float* g1  = (const float*)d_in[8];
  const float* be1 = (const float*)d_in[9];
  const float* w2  = (const float*)d_in[10];
  const float* b2  = (const float*)d_in[11];
  const float* g2  = (const float*)d_in[12];
  const float* be2 = (const float*)d_in[13];

  float* out  = (float*)d_out;
  float* nxz  = out;                 // (B,S,3)
  float* out2 = out + BB * SS * 3;   // (B,S,128)

  float* ws    = (float*)d_ws;
  float* stats = ws;                 // 512 floats, zeroed every call
  float* par   = ws;                 // params addressed via OFF_* macros
  float* zmax  = ws + OFF_ZMAX;
  float* feat  = ws + OFF_FEAT;

  hipMemsetAsync(stats, 0, 512 * sizeof(float), stream);

  // 128 KiB dynamic LDS: float2 (x,y) per point; z+d stay in VGPRs
  fps_kernel<<<BB, 1024, NPT * sizeof(float2), stream>>>(xyz, nxz);
  ballq_kernel<<<2048, 256, 0, stream>>>(xyz, pts, nxz, feat);

  mlp1s_kernel<<<256, 256, 0, stream>>>(feat, w0, b0, stats);
  fin_kernel<<<1, 64, 0, stream>>>(g0, be0, stats + OFF_S1, stats + OFF_Q1,
                                   par + OFF_A1, par + OFF_C1, 64);
  mlp2s_kernel<<<512, 256, 0, stream>>>(feat, w0, b0, w1, b1, par, stats);
  fin_kernel<<<1, 64, 0, stream>>>(g1, be1, stats + OFF_S2, stats + OFF_Q2,
                                   par + OFF_A2, par + OFF_C2, 64);
  mlp3f_kernel<<<512, 256, 0, stream>>>(feat, w0, b0, w1, b1, w2, b2, par, stats, zmax);
  fin_kernel<<<1, 128, 0, stream>>>(g2, be2, stats + OFF_S3, stats + OFF_Q3,
                                    par + OFF_A3, par + OFF_C3, 128);
  final_out_kernel<<<4096, 256, 0, stream>>>(zmax, par, out2);
}

// Round 3
// 2114.300 us; speedup vs baseline: 1.4165x; 1.4165x over previous
//
#include <hip/hip_runtime.h>
#include <stdint.h>

// Forbid mul+add contraction: distance arithmetic must match the numpy
// reference bit-for-bit (argmax / radius-compare are discontinuous).
// MLP math uses explicit fmaf() (exact FMA is fine; only ordering matters).
#pragma clang fp contract(off)

#define NPT   16384
#define BB    8
#define SS    1024
#define KSAMP 32
#define PTOT  (BB*SS*KSAMP)   // 262144
#define NGRP  (BB*SS)         // 8192
#define R2    0.04f
#define EPSBN 1e-5f
#define INV_M 3.814697265625e-06f   // 1/262144, exact power of two

// ws layout (floats)
#define OFF_S1 0
#define OFF_Q1 64
#define OFF_S2 128
#define OFF_Q2 192
#define OFF_S3 256    // 128
#define OFF_Q3 384    // 128
#define OFF_A1 512
#define OFF_C1 576
#define OFF_A2 640
#define OFF_C2 704
#define OFF_A3 768    // 128
#define OFF_C3 896    // 128
#define OFF_ZMAX 1024                  // 8192*128 = 1048576
#define OFF_FEAT (1024 + 1048576)      // 6*262144 = 1572864  (total ~10.5 MB)

// ---------------------------------------------------------------------------
// helpers
// ---------------------------------------------------------------------------
__device__ __forceinline__ float wave_sum(float v) {
#pragma unroll
  for (int off = 32; off; off >>= 1) v += __shfl_xor(v, off);
  return v;  // butterfly: all lanes hold identical total
}
__device__ __forceinline__ float half_max(float v) {
#pragma unroll
  for (int off = 16; off; off >>= 1) v = fmaxf(v, __shfl_xor(v, off));
  return v;  // max within each 32-lane half
}

// Canonical GCN wave64 max reduction in VALU-speed DPP (no DS hops):
// row_shr 1/2/4/8 reduce within 16-lane rows (lane15/31/47/63 hold row max),
// row_bcast15 merges row0->row1 / row2->row3, row_bcast31 merges lower32->
// upper32; lane 63 then holds the full-wave max. bound_ctrl=1 fills 0, which
// is harmless: all inputs are squared distances >= 0.
// Cost ~6 chained VALU (~60cy) vs 6 chained ds_bpermute (~720cy @120cy each).
__device__ __forceinline__ float wave_max_dpp(float x) {
  int v = __float_as_int(x), t;
  t = __builtin_amdgcn_update_dpp(0, v, 0x111, 0xf, 0xf, true);  // row_shr:1
  v = __float_as_int(fmaxf(__int_as_float(v), __int_as_float(t)));
  t = __builtin_amdgcn_update_dpp(0, v, 0x112, 0xf, 0xf, true);  // row_shr:2
  v = __float_as_int(fmaxf(__int_as_float(v), __int_as_float(t)));
  t = __builtin_amdgcn_update_dpp(0, v, 0x114, 0xf, 0xf, true);  // row_shr:4
  v = __float_as_int(fmaxf(__int_as_float(v), __int_as_float(t)));
  t = __builtin_amdgcn_update_dpp(0, v, 0x118, 0xf, 0xf, true);  // row_shr:8
  v = __float_as_int(fmaxf(__int_as_float(v), __int_as_float(t)));
  t = __builtin_amdgcn_update_dpp(0, v, 0x142, 0xf, 0xf, true);  // row_bcast:15
  v = __float_as_int(fmaxf(__int_as_float(v), __int_as_float(t)));
  t = __builtin_amdgcn_update_dpp(0, v, 0x143, 0xf, 0xf, true);  // row_bcast:31
  v = __float_as_int(fmaxf(__int_as_float(v), __int_as_float(t)));
  return __int_as_float(__builtin_amdgcn_readlane(v, 63));
}

// ---------------------------------------------------------------------------
// 1) Farthest point sampling. R3 POST-MORTEM: shuffle butterflies are
//    ds_bpermute chains at ~120cy/hop (m117 LDS latency); R2's reduce had
//    ~20 serial hops ~= 2400cy/iter — the dominant cost, not VALU.
//    R4 STRUCTURE (tail with ~zero serial DS hops):
//    - inner loop unchanged: value-only, xy from LDS (imm-offset ds_read_b64),
//      z/d in VGPRs. 10 VALU/pt, issue ~1280cy/SIMD/iter.
//    - wave max via DPP (VALU) + readlane -> SGPR.
//    - block max: lane0 of each wave does ds_atomic_max_u32 on ONE LDS word
//      (u32 order == f32 order for values >= 0); merges in-pipe pre-barrier.
//    - argmax index + winner z: threads whose bv bit-equals blockmax scan
//      their d[j] (inline-const cndmask, lowest j) and issue ONE
//      ds_atomic_min_u64 with key = (idx<<32)|z_bits: min key = lowest
//      global index (== jnp.argmax first-occurrence, exact tie handling),
//      and the winner's exact z rides in the low word -> no z publish dance,
//      no global centroid fetch. cx,cy via one LDS broadcast read.
//    - 2 barriers/iter; double-buffered bmax/wkey, resets inside the (A,B)
//      epoch so no slot is ever written and read in the same epoch.
//    Distance arithmetic order unchanged (bit-exact): (dx*dx+dy*dy)+dz*dz,
//    fminf, centroid coords bitwise-identical copies via LDS/atomic payload.
// ---------------------------------------------------------------------------
__global__ __launch_bounds__(1024)
void fps_kernel(const float* __restrict__ xyz, float* __restrict__ newxyz) {
  extern __shared__ float smem[];          // 128 KiB dynamic: float2 sxy[NPT]
  float2* sxy = (float2*)smem;
  __shared__ unsigned bmax[2];             // block max (f32 bits, >=0)
  __shared__ unsigned long long wkey[2];   // (min idx << 32) | z bits
  const int b = blockIdx.x;
  const int t = threadIdx.x;
  const int lane = t & 63;
  const float* xb = xyz + (size_t)b * NPT * 3;

  float z[16], d[16];
#pragma unroll
  for (int j = 0; j < 16; ++j) {
    int p = j * 1024 + t;
    float xx = xb[3 * p];
    float yy = xb[3 * p + 1];
    float zz = xb[3 * p + 2];
    sxy[p] = make_float2(xx, yy);
    z[j] = zz;
    d[j] = 1e10f;
    asm volatile("" : "+v"(z[j]));        // keep z materialized in a VGPR
  }

  // initial centroid = point 0 (uniform broadcast loads, once)
  float cx = xb[0], cy = xb[1], cz = xb[2];
  if (t == 0) {
    bmax[0] = bmax[1] = 0u;
    wkey[0] = wkey[1] = ~0ull;
    float* o = newxyz + (size_t)b * SS * 3;
    o[0] = cx; o[1] = cy; o[2] = cz;
  }
  __syncthreads();                         // sxy + slots visible to all waves

  // two bases so every ds_read_b64 gets an immediate offset < 64KiB
  const float2* pA = sxy + t;
  const float2* pB = sxy + t + 8192;

  for (int it = 1; it < SS; ++it) {
    const int buf = it & 1;
    float bv = 0.0f;                       // distances >= 0
#pragma unroll
    for (int j = 0; j < 16; ++j) {
      float2 xy = (j < 8) ? pA[j * 1024] : pB[(j - 8) * 1024];
      float dx = xy.x - cx, dy = xy.y - cy, dz = z[j] - cz;
      float d2 = (dx * dx + dy * dy) + dz * dz;   // matches numpy order
      float dm = fminf(d[j], d2);
      d[j] = dm;
      bv = fmaxf(bv, dm);                 // value-only tracking
    }
    float wm = wave_max_dpp(bv);          // VALU-only wave reduce
    if (lane == 0) atomicMax(&bmax[buf], __float_as_uint(wm));  // ds_max_u32
    __syncthreads();                      // A: all wave maxes merged
    if (t == 0) { bmax[buf ^ 1] = 0u; wkey[buf ^ 1] = ~0ull; }  // prep next
    const unsigned bmu = bmax[buf];
    if (__float_as_uint(bv) == bmu) {     // only max-holders scan (rare)
      int bj = 0; float zc = z[0];
#pragma unroll
      for (int j = 15; j >= 0; --j)       // descending -> lowest j wins
        if (__float_as_uint(d[j]) == bmu) { bj = j; zc = z[j]; }
      unsigned long long key =
          ((unsigned long long)(unsigned)(bj * 1024 + t) << 32) |
          (unsigned long long)__float_as_uint(zc);
      atomicMin(&wkey[buf], key);         // ds_min_u64: idx-major
    }
    __syncthreads();                      // B: winner resolved
    unsigned long long k = wkey[buf];
    int fi = (int)(unsigned)(k >> 32);
    cz = __uint_as_float((unsigned)k);    // winner's exact z
    fi = __builtin_amdgcn_readfirstlane(fi);
    float2 cxy = sxy[fi];                 // LDS broadcast read
    cx = cxy.x; cy = cxy.y;
    if (t == 0) {
      float* o = newxyz + ((size_t)b * SS + it) * 3;
      o[0] = cx; o[1] = cy; o[2] = cz;
    }
  }
}

// ---------------------------------------------------------------------------
// 2) Ball query + gather (fused): one wave per centroid, ascending-index scan
//    with ballot == ref's sort+slice. feat is channel-major [6][PTOT].
// ---------------------------------------------------------------------------
__global__ __launch_bounds__(256, 2)
void ballq_kernel(const float* __restrict__ xyz, const float* __restrict__ pts,
                  const float* __restrict__ newxyz, float* __restrict__ feat) {
  const int lane = threadIdx.x & 63;
  const int c = blockIdx.x * 4 + (threadIdx.x >> 6);  // 0..8191
  const int b = c >> 10;
  const float* xb = xyz + (size_t)b * NPT * 3;
  const float* pb = pts + (size_t)b * NPT * 3;
  const float cx = newxyz[3 * c], cy = newxyz[3 * c + 1], cz = newxyz[3 * c + 2];
  const int base = c * KSAMP;
  const uint64_t ltm = (1ull << lane) - 1ull;

  int cnt = 0, firstp = 0;
  bool haveFirst = false;
  for (int p0 = 0; p0 < NPT && cnt < KSAMP; p0 += 64) {
    int p = p0 + lane;
    float px = xb[3 * p], py = xb[3 * p + 1], pz = xb[3 * p + 2];
    float dx = cx - px, dy = cy - py, dz = cz - pz;
    float sqr = (dx * dx + dy * dy) + dz * dz;
    bool in = (sqr <= R2);                          // !(sqr > r^2)
    uint64_t m = __ballot(in);
    if (!haveFirst && m) { firstp = p0 + (__ffsll((unsigned long long)m) - 1); haveFirst = true; }
    int rank = (int)__popcll(m & ltm);
    int slot = cnt + rank;
    if (in && slot < KSAMP) {
      int idx = base + slot;
      feat[0 * PTOT + idx] = px - cx;
      feat[1 * PTOT + idx] = py - cy;
      feat[2 * PTOT + idx] = pz - cz;
      feat[3 * PTOT + idx] = pb[3 * p];
      feat[4 * PTOT + idx] = pb[3 * p + 1];
      feat[5 * PTOT + idx] = pb[3 * p + 2];
    }
    cnt += (int)__popcll(m);
  }
  if (cnt < KSAMP) {  // pad with first in-ball point (center itself qualifies)
    int slot = cnt + lane;
    if (slot < KSAMP) {
      int idx = base + slot;
      float px = xb[3 * firstp], py = xb[3 * firstp + 1], pz = xb[3 * firstp + 2];
      feat[0 * PTOT + idx] = px - cx;
      feat[1 * PTOT + idx] = py - cy;
      feat[2 * PTOT + idx] = pz - cz;
      feat[3 * PTOT + idx] = pb[3 * firstp];
      feat[4 * PTOT + idx] = pb[3 * firstp + 1];
      feat[5 * PTOT + idx] = pb[3 * firstp + 2];
    }
  }
}

// ---------------------------------------------------------------------------
// 3) stats of layer-1 pre-activations. Per-thread s[64],q[64] (cheap here:
//    only 6 FMA per channel). Block-reduce -> global atomics.
// ---------------------------------------------------------------------------
__global__ __launch_bounds__(256, 2)
void mlp1s_kernel(const float* __restrict__ feat, const float* __restrict__ w0,
                  const float* __restrict__ b0, float* __restrict__ stats) {
  float s[64], q[64];
#pragma unroll
  for (int o = 0; o < 64; ++o) { s[o] = 0.0f; q[o] = 0.0f; }
  int gid = blockIdx.x * 256 + threadIdx.x;
  for (int p = gid; p < PTOT; p += 256 * 256) {
    float f[6];
#pragma unroll
    for (int ch = 0; ch < 6; ++ch) f[ch] = feat[ch * PTOT + p];
#pragma unroll
    for (int o = 0; o < 64; ++o) {
      float z = b0[o];
#pragma unroll
      for (int i = 0; i < 6; ++i) z = fmaf(w0[o * 6 + i], f[i], z);
      s[o] += z; q[o] = fmaf(z, z, q[o]);
    }
  }
  const int lane = threadIdx.x & 63;
#pragma unroll
  for (int o = 0; o < 64; ++o) { s[o] = wave_sum(s[o]); q[o] = wave_sum(q[o]); }
  __shared__ float ls[128];
  if (threadIdx.x < 128) ls[threadIdx.x] = 0.0f;
  __syncthreads();
  if (lane == 0) {
#pragma unroll
    for (int o = 0; o < 64; ++o) { atomicAdd(&ls[o], s[o]); atomicAdd(&ls[64 + o], q[o]); }
  }
  __syncthreads();
  if (threadIdx.x < 64) atomicAdd(&stats[OFF_S1 + threadIdx.x], ls[threadIdx.x]);
  else if (threadIdx.x < 128) atomicAdd(&stats[OFF_Q1 + threadIdx.x - 64], ls[threadIdx.x]);
}

// ---------------------------------------------------------------------------
// BN fold: a = g/sqrt(var+eps), c = be - a*mu   (h = relu(a*z + c))
// ---------------------------------------------------------------------------
__global__ void fin_kernel(const float* __restrict__ g, const float* __restrict__ be,
                           const float* __restrict__ s, const float* __restrict__ q,
                           float* __restrict__ A, float* __restrict__ C, int Cn) {
  int o = blockIdx.x * blockDim.x + threadIdx.x;
  if (o >= Cn) return;
  float mu = s[o] * INV_M;
  float var = q[o] * INV_M - mu * mu;
  float a = g[o] / sqrtf(var + EPSBN);
  A[o] = a;
  C[o] = be[o] - a * mu;
}

// ---------------------------------------------------------------------------
// 4) stats of layer-2 pre-activations. h1 built explicitly (unrolled o),
//    then rolled-o loop: scalar z2 accumulators + wave-butterfly stats into
//    designated-lane registers.
// ---------------------------------------------------------------------------
__global__ __launch_bounds__(256, 2)
void mlp2s_kernel(const float* __restrict__ feat,
                  const float* __restrict__ w0, const float* __restrict__ b0,
                  const float* __restrict__ w1, const float* __restrict__ b1,
                  const float* __restrict__ par, float* __restrict__ stats) {
  const float* a1 = par + OFF_A1;
  const float* c1 = par + OFF_C1;
  const int lane = threadIdx.x & 63;
  float sp = 0.0f, qp = 0.0f;          // this lane's channel (== lane)
  int gid = blockIdx.x * 256 + threadIdx.x;
  for (int p = gid; p < PTOT; p += 512 * 256) {
    float f[6];
#pragma unroll
    for (int ch = 0; ch < 6; ++ch) f[ch] = feat[ch * PTOT + p];
    float h1[64];
#pragma unroll
    for (int o = 0; o < 64; ++o) {
      float z = b0[o];
#pragma unroll
      for (int i = 0; i < 6; ++i) z = fmaf(w0[o * 6 + i], f[i], z);
      h1[o] = fmaxf(fmaf(a1[o], z, c1[o]), 0.0f);
    }
    for (int o = 0; o < 64; o += 2) {   // rolled: scalar temps only
      float z0 = b1[o], z1 = b1[o + 1];
#pragma unroll
      for (int i = 0; i < 64; ++i) {
        z0 = fmaf(w1[o * 64 + i], h1[i], z0);
        z1 = fmaf(w1[(o + 1) * 64 + i], h1[i], z1);
      }
      float s0 = wave_sum(z0), q0 = wave_sum(z0 * z0);
      float s1 = wave_sum(z1), q1 = wave_sum(z1 * z1);
      if (lane == o)     { sp += s0; qp += q0; }
      if (lane == o + 1) { sp += s1; qp += q1; }
    }
  }
  atomicAdd(&stats[OFF_S2 + lane], sp);
  atomicAdd(&stats[OFF_Q2 + lane], qp);
}

// ---------------------------------------------------------------------------
// 5) layer-3 fused: recompute h1 (per-i, no array), accumulate h2[64]
//    (i-rolled, o-unrolled), then rolled-o layer-3 with butterfly stats +
//    half-wave max. Writes zmax[g][o] (raw pre-BN max; valid because a3>0
//    makes relu(a*z+c) monotone).
// ---------------------------------------------------------------------------
__global__ __launch_bounds__(256, 2)
void mlp3f_kernel(const float* __restrict__ feat,
                  const float* __restrict__ w0, const float* __restrict__ b0,
                  const float* __restrict__ w1, const float* __restrict__ b1,
                  const float* __restrict__ w2, const float* __restrict__ b2,
                  const float* __restrict__ par, float* __restrict__ stats,
                  float* __restrict__ zmax) {
  const float* a1 = par + OFF_A1;
  const float* c1 = par + OFF_C1;
  const float* a2 = par + OFF_A2;
  const float* c2 = par + OFF_C2;
  const int lane = threadIdx.x & 63;
  float sp0 = 0.0f, qp0 = 0.0f;        // channel lane
  float sp1 = 0.0f, qp1 = 0.0f;        // channel 64+lane
  int gid = blockIdx.x * 256 + threadIdx.x;
  for (int p = gid; p < PTOT; p += 512 * 256) {
    float f[6];
#pragma unroll
    for (int ch = 0; ch < 6; ++ch) f[ch] = feat[ch * PTOT + p];
    float h2[64];
#pragma unroll
    for (int o = 0; o < 64; ++o) h2[o] = b1[o];
    for (int i = 0; i < 64; ++i) {      // rolled; h1[i] recomputed (8 instr)
      float z = b0[i];
#pragma unroll
      for (int ch = 0; ch < 6; ++ch) z = fmaf(w0[i * 6 + ch], f[ch], z);
      float h1i = fmaxf(fmaf(a1[i], z, c1[i]), 0.0f);
#pragma unroll
      for (int o = 0; o < 64; ++o) h2[o] = fmaf(w1[o * 64 + i], h1i, h2[o]);
    }
#pragma unroll
    for (int o = 0; o < 64; ++o) h2[o] = fmaxf(fmaf(a2[o], h2[o], c2[o]), 0.0f);

    const int g = p >> 5;               // this lane's group
    for (int o = 0; o < 128; o += 2) {  // rolled: scalar temps
      float z0 = b2[o], z1 = b2[o + 1];
#pragma unroll
      for (int i = 0; i < 64; ++i) {
        z0 = fmaf(w2[o * 64 + i], h2[i], z0);
        z1 = fmaf(w2[(o + 1) * 64 + i], h2[i], z1);
      }
      float s0 = wave_sum(z0), q0 = wave_sum(z0 * z0);
      float s1 = wave_sum(z1), q1 = wave_sum(z1 * z1);
      if (lane == (o & 63))       { if (o < 64) { sp0 += s0; qp0 += q0; } else { sp1 += s0; qp1 += q0; } }
      if (lane == ((o + 1) & 63)) { if (o < 64) { sp0 += s1; qp0 += q1; } else { sp1 += s1; qp1 += q1; } }
      float m0 = half_max(z0), m1 = half_max(z1);
      if ((lane & 31) == (o & 31))       zmax[g * 128 + o]     = m0;
      if ((lane & 31) == ((o + 1) & 31)) zmax[g * 128 + o + 1] = m1;
    }
  }
  atomicAdd(&stats[OFF_S3 + lane], sp0);
  atomicAdd(&stats[OFF_Q3 + lane], qp0);
  atomicAdd(&stats[OFF_S3 + 64 + lane], sp1);
  atomicAdd(&stats[OFF_Q3 + 64 + lane], qp1);
}

// ---------------------------------------------------------------------------
// 6) epilogue: out2[g][c] = relu(a3[c]*zmax[g][c] + c3[c])
// ---------------------------------------------------------------------------
__global__ __launch_bounds__(256, 4)
void final_out_kernel(const float* __restrict__ zmax, const float* __restrict__ par,
                      float* __restrict__ out2) {
  const float* a3 = par + OFF_A3;
  const float* c3 = par + OFF_C3;
  int idx = blockIdx.x * 256 + threadIdx.x;   // g*128 + c
  int c = idx & 127;
  out2[idx] = fmaxf(fmaf(a3[c], zmax[idx], c3[c]), 0.0f);
}

// ---------------------------------------------------------------------------
extern "C" void kernel_launch(void* const* d_in, const int* in_sizes, int n_in,
                              void* d_out, int out_size, void* d_ws, size_t ws_size,
                              hipStream_t stream) {
  const float* xyz = (const float*)d_in[0];
  const float* pts = (const float*)d_in[1];
  const float* w0  = (const float*)d_in[2];
  const float* b0  = (const float*)d_in[3];
  const float* g0  = (const float*)d_in[4];
  const float* be0 = (const float*)d_in[5];
  const float* w1  = (const float*)d_in[6];
  const float* b1  = (const float*)d_in[7];
  const float* g1  = (const float*)d_in[8];
  const float* be1 = (const float*)d_in[9];
  const float* w2  = (const float*)d_in[10];
  const float* b2  = (const float*)d_in[11];
  const float* g2  = (const float*)d_in[12];
  const float* be2 = (const float*)d_in[13];

  float* out  = (float*)d_out;
  float* nxz  = out;                 // (B,S,3)
  float* out2 = out + BB * SS * 3;   // (B,S,128)

  float* ws    = (float*)d_ws;
  float* stats = ws;                 // 512 floats, zeroed every call
  float* par   = ws;                 // params addressed via OFF_* macros
  float* zmax  = ws + OFF_ZMAX;
  float* feat  = ws + OFF_FEAT;

  hipMemsetAsync(stats, 0, 512 * sizeof(float), stream);

  // 128 KiB dynamic LDS: float2 (x,y) per point; z+d stay in VGPRs
  fps_kernel<<<BB, 1024, NPT * sizeof(float2), stream>>>(xyz, nxz);
  ballq_kernel<<<2048, 256, 0, stream>>>(xyz, pts, nxz, feat);

  mlp1s_kernel<<<256, 256, 0, stream>>>(feat, w0, b0, stats);
  fin_kernel<<<1, 64, 0, stream>>>(g0, be0, stats + OFF_S1, stats + OFF_Q1,
                                   par + OFF_A1, par + OFF_C1, 64);
  mlp2s_kernel<<<512, 256, 0, stream>>>(feat, w0, b0, w1, b1, par, stats);
  fin_kernel<<<1, 64, 0, stream>>>(g1, be1, stats + OFF_S2, stats + OFF_Q2,
                                   par + OFF_A2, par + OFF_C2, 64);
  mlp3f_kernel<<<512, 256, 0, stream>>>(feat, w0, b0, w1, b1, w2, b2, par, stats, zmax);
  fin_kernel<<<1, 128, 0, stream>>>(g2, be2, stats + OFF_S3, stats + OFF_Q3,
                                    par + OFF_A3, par + OFF_C3, 128);
  final_out_kernel<<<4096, 256, 0, stream>>>(zmax, par, out2);
}